// Round 1
// baseline (197.306 us; speedup 1.0000x reference)
//
#include <hip/hip_runtime.h>
#include <cstdint>

// GRU RNN fused persistent kernel for MI355X (gfx950).
// T=256, B=4096, D=128, H=16. Gate order along 3H: r, z, n (torch GRUCell).
//
// Design:
//  - grid 256 blocks (1/CU), 256 threads (4 waves). Block owns 16 batch lanes
//    across all T. h state in LDS, W_hh rows in VGPRs.
//  - per chunk of Tc=8 steps: gx = feat@Wih^T via MFMA 16x16x32 bf16,
//    3-pass hi/lo split for f32-exact results; then 8 sequential scan steps.
//  - feat chunk (64KB f32) staged by async global_load_lds (width 16) into a
//    SINGLE LDS buffer; prefetch of chunk c+1 is issued after chunk c's MFMA
//    phase and overlaps the scan. Raw s_barrier + manual waitcnt so scan
//    barriers don't drain vmcnt (m201-template style).
//  - A-tile reads would be 16-way bank-conflicted (512B rows); fixed by
//    XOR-swizzling 16B granules: pre-swizzled GLOBAL source addrs (linear LDS
//    dest, G21) + same XOR applied on ds_read_b128 (2-way -> free).

#define TT 256
#define BB 4096
#define DD 128
#define HH 16
#define TC 8
#define NCH (TT / TC)
#define EPB 16

typedef float    f32x4  __attribute__((ext_vector_type(4)));
typedef short    bf16x8 __attribute__((ext_vector_type(8)));
typedef uint32_t u32x4  __attribute__((ext_vector_type(4)));

__device__ __forceinline__ float sigf(float x) {
  return 1.0f / (1.0f + __expf(-x));
}

__device__ __forceinline__ void stage_chunk(const float* __restrict__ feat,
                                            const float* __restrict__ bmask,
                                            float* As, float* msbuf,
                                            int c, int b0, int lane, int wv) {
  // A-tile: 128 rows (row = tq*16 + e) x 128 f32, 64 segments of 1KB.
  // LDS dest linear; global source pre-swizzled: granule g of row r comes from
  // global byte offset (g*16) ^ ((r&7)<<4) within the row.
  const char* base =
      (const char*)(feat + (size_t)c * TC * BB * DD + (size_t)b0 * DD);
#pragma unroll
  for (int k = 0; k < 16; ++k) {
    int s = wv * 16 + k;                 // wave-uniform segment id
    int row = 2 * s + (lane >> 5);       // 0..127
    int e = row & 15, tq = row >> 4;
    int inrow = (lane & 31) << 4;        // byte offset within 512B row
    int off = e * (DD * 4) + (inrow ^ ((row & 7) << 4));
    const char* g = base + (size_t)tq * ((size_t)BB * DD * 4) + off;
    __builtin_amdgcn_global_load_lds(
        (const __attribute__((address_space(1))) void*)g,
        (__attribute__((address_space(3))) void*)((char*)As + s * 1024),
        16, 0, 0);
  }
  if (wv == 0) {
    // begin_mask chunk: 8t x 16e floats -> msbuf[tq*16+e]
#pragma unroll
    for (int k2 = 0; k2 < 2; ++k2) {
      int idx = k2 * 64 + lane;
      int tq = idx >> 4, e = idx & 15;
      const char* g = (const char*)(bmask + (size_t)(c * TC + tq) * BB + b0 + e);
      __builtin_amdgcn_global_load_lds(
          (const __attribute__((address_space(1))) void*)g,
          (__attribute__((address_space(3))) void*)((char*)msbuf + k2 * 256),
          4, 0, 0);
    }
  }
}

__global__ __launch_bounds__(256, 1) void gru_fused(
    const float* __restrict__ feat, const float* __restrict__ bmask,
    const float* __restrict__ hx0, const float* __restrict__ Wih,
    const float* __restrict__ Whh, const float* __restrict__ bih,
    const float* __restrict__ bhh, float* __restrict__ out) {
  __shared__ __align__(16) float As[TC * EPB * DD];       // 64 KB (swizzled)
  __shared__ __align__(16) float gxs[TC * EPB * 48];      // 24 KB
  __shared__ __align__(16) unsigned short Whi[48 * 136];  // 12.75 KB (pad 136)
  __shared__ __align__(16) unsigned short Wlo[48 * 136];  // 12.75 KB
  __shared__ __align__(16) float hs[EPB * HH];            // 1 KB
  __shared__ __align__(16) float ms[2][TC * EPB];         // 1 KB (dbuf)

  const int tid  = threadIdx.x;
  const int lane = tid & 63;
  const int wv   = tid >> 6;   // wave 0..3
  const int li   = lane & 15;  // MFMA fragment row/col index
  const int lq   = lane >> 4;  // MFMA quarter 0..3
  const int b0   = blockIdx.x * EPB;
  const int si   = tid & 15;   // scan: hidden index i
  const int se   = tid >> 4;   // scan: element 0..15

  // ---- prologue: split W_ih into bf16 hi/lo planes in LDS ----
  for (int idx = tid; idx < 48 * DD; idx += 256) {
    int g = idx >> 7, k = idx & 127;
    float w = Wih[idx];
    uint32_t u = __float_as_uint(w);
    uint32_t h = u & 0xFFFF0000u;           // trunc-to-bf16 (hi)
    float l = w - __uint_as_float(h);       // exact remainder
    Whi[g * 136 + k] = (unsigned short)(h >> 16);
    Wlo[g * 136 + k] = (unsigned short)(__float_as_uint(l) >> 16);
  }
  // per-thread W_hh rows (g = si, si+16, si+32) and biases in registers
  float whh[3][16];
  float bh3[3], bi3[3];
#pragma unroll
  for (int c3 = 0; c3 < 3; ++c3) {
    bh3[c3] = bhh[si + 16 * c3];
#pragma unroll
    for (int j = 0; j < 16; ++j) whh[c3][j] = Whh[(si + 16 * c3) * HH + j];
  }
#pragma unroll
  for (int n = 0; n < 3; ++n) bi3[n] = bih[16 * n + li];
  hs[se * HH + si] = hx0[(b0 + se) * HH + si];

  stage_chunk(feat, bmask, As, ms[0], 0, b0, lane, wv);
  __syncthreads();  // full drain: prologue LDS + chunk-0 DMA visible

  for (int c = 0; c < NCH; ++c) {
    // ================= MFMA phase: gx = A @ Wih^T + b_ih =================
    f32x4 acc[2][3];
#pragma unroll
    for (int m = 0; m < 2; ++m)
#pragma unroll
      for (int n = 0; n < 3; ++n) acc[m][n] = (f32x4){0.f, 0.f, 0.f, 0.f};

#pragma unroll
    for (int ks = 0; ks < 4; ++ks) {  // K slices of 32
      bf16x8 Bh[3], Bl[3];
#pragma unroll
      for (int n = 0; n < 3; ++n) {   // N tiles (gate groups of 16)
        int g = 16 * n + li;
        int wb = g * 272 + ks * 64 + lq * 16;
        Bh[n] = *(const bf16x8*)((const char*)Whi + wb);
        Bl[n] = *(const bf16x8*)((const char*)Wlo + wb);
      }
#pragma unroll
      for (int m = 0; m < 2; ++m) {   // wave's two M tiles
        int row = (2 * wv + m) * 16 + li;
        int colb = ks * 128 + lq * 32;
        int a0o = row * 512 + (colb ^ ((row & 7) << 4));  // swizzled read
        f32x4 x0 = *(const f32x4*)((const char*)As + a0o);
        f32x4 x1 = *(const f32x4*)((const char*)As + (a0o ^ 16));
        float xs[8] = {x0.x, x0.y, x0.z, x0.w, x1.x, x1.y, x1.z, x1.w};
        uint32_t hi[4], lo[4];
#pragma unroll
        for (int j = 0; j < 4; ++j) {
          uint32_t e0 = __float_as_uint(xs[2 * j]);
          uint32_t e1 = __float_as_uint(xs[2 * j + 1]);
          uint32_t h0 = e0 & 0xFFFF0000u, h1 = e1 & 0xFFFF0000u;
          hi[j] = (h0 >> 16) | h1;
          float l0f = xs[2 * j] - __uint_as_float(h0);
          float l1f = xs[2 * j + 1] - __uint_as_float(h1);
          lo[j] = (__float_as_uint(l0f) >> 16) |
                  (__float_as_uint(l1f) & 0xFFFF0000u);
        }
        bf16x8 Ah = __builtin_bit_cast(bf16x8, (u32x4){hi[0], hi[1], hi[2], hi[3]});
        bf16x8 Al = __builtin_bit_cast(bf16x8, (u32x4){lo[0], lo[1], lo[2], lo[3]});
#pragma unroll
        for (int n = 0; n < 3; ++n) {  // 3-pass split: hh + lh + hl
          acc[m][n] = __builtin_amdgcn_mfma_f32_16x16x32_bf16(Ah, Bh[n], acc[m][n], 0, 0, 0);
          acc[m][n] = __builtin_amdgcn_mfma_f32_16x16x32_bf16(Al, Bh[n], acc[m][n], 0, 0, 0);
          acc[m][n] = __builtin_amdgcn_mfma_f32_16x16x32_bf16(Ah, Bl[n], acc[m][n], 0, 0, 0);
        }
      }
    }
    // write gx (+bias) to LDS: D row = (lq*4 + j), col = li (m89-verified)
#pragma unroll
    for (int m = 0; m < 2; ++m) {
      int rowb = (2 * wv + m) * 16 + lq * 4;
#pragma unroll
      for (int n = 0; n < 3; ++n)
#pragma unroll
        for (int j = 0; j < 4; ++j)
          gxs[(rowb + j) * 48 + 16 * n + li] = acc[m][n][j] + bi3[n];
    }
    asm volatile("s_waitcnt lgkmcnt(0)" ::: "memory");
    __builtin_amdgcn_s_barrier();  // gx visible; A-tile dead -> reusable

    // issue async prefetch of next chunk; lands during the scan below
    if (c + 1 < NCH)
      stage_chunk(feat, bmask, As, ms[(c + 1) & 1], c + 1, b0, lane, wv);

    // ================= sequential scan: 8 steps =================
    const float* msrd = ms[c & 1];
#pragma unroll
    for (int tq = 0; tq < TC; ++tq) {
      float mv = msrd[tq * 16 + se];
      float f = 1.0f - mv;  // begin-of-episode reset factor
      float d0 = 0.f, d1 = 0.f, d2 = 0.f;
#pragma unroll
      for (int q = 0; q < 4; ++q) {
        f32x4 hq = *(const f32x4*)&hs[se * HH + 4 * q];
#pragma unroll
        for (int j = 0; j < 4; ++j) {
          float hj = hq[j];
          d0 = __builtin_fmaf(whh[0][4 * q + j], hj, d0);
          d1 = __builtin_fmaf(whh[1][4 * q + j], hj, d1);
          d2 = __builtin_fmaf(whh[2][4 * q + j], hj, d2);
        }
      }
      float hm = f * hs[se * HH + si];  // masked h_i for the z*h term
      int gb = (tq * 16 + se) * 48;
      float g0 = gxs[gb + si];
      float g1 = gxs[gb + 16 + si];
      float g2 = gxs[gb + 32 + si];
      float r = sigf(g0 + f * d0 + bh3[0]);
      float z = sigf(g1 + f * d1 + bh3[1]);
      float a = g2 + r * (f * d2 + bh3[2]);
      float n = 2.0f / (1.0f + __expf(-2.0f * a)) - 1.0f;  // tanh
      float hn = n + z * (hm - n);  // (1-z)*n + z*h
      // all LDS reads of this step must land before anyone overwrites h
      asm volatile("s_waitcnt lgkmcnt(0)" ::: "memory");
      __builtin_amdgcn_s_barrier();
      hs[se * HH + si] = hn;
      out[((size_t)(c * TC + tq) * BB + b0 + se) * HH + si] = hn;
      asm volatile("s_waitcnt lgkmcnt(0)" ::: "memory");
      __builtin_amdgcn_s_barrier();
    }

    // next chunk's A-tile (and mask) must be fully landed
    asm volatile("s_waitcnt vmcnt(0)" ::: "memory");
    __builtin_amdgcn_s_barrier();
  }
}

extern "C" void kernel_launch(void* const* d_in, const int* in_sizes, int n_in,
                              void* d_out, int out_size, void* d_ws,
                              size_t ws_size, hipStream_t stream) {
  const float* feat  = (const float*)d_in[0];
  const float* bmask = (const float*)d_in[1];
  const float* hx0   = (const float*)d_in[2];
  const float* Wih   = (const float*)d_in[3];
  const float* Whh   = (const float*)d_in[4];
  const float* bih   = (const float*)d_in[5];
  const float* bhh   = (const float*)d_in[6];
  float* out = (float*)d_out;
  gru_fused<<<dim3(BB / EPB), dim3(256), 0, stream>>>(feat, bmask, hx0, Wih,
                                                      Whh, bih, bhh, out);
}